// Round 12
// baseline (990.805 us; speedup 1.0000x reference)
//
#include <hip/hip_runtime.h>
#include <stdint.h>

#define NLAYER 5
#define EMB    300
#define EMBP   320
#define EMBP2  384
#define HID    600
#define HIDP   640
#define BNEPS  1e-5f

typedef _Float16 f16;
typedef __attribute__((ext_vector_type(8))) _Float16 hfrag;
typedef __attribute__((ext_vector_type(4))) float f32x4;

__device__ __forceinline__ void gload16(const void* g, void* l){
  __builtin_amdgcn_global_load_lds(
      (const __attribute__((address_space(1))) void*)g,
      (__attribute__((address_space(3))) void*)l,
      16, 0, 0);
}

// ---------------- setup kernels ----------------

__global__ void k_zero(unsigned int* __restrict__ p, int n){
  int i = blockIdx.x*blockDim.x + threadIdx.x;
  if (i < n) p[i] = 0u;
}

__global__ void k_hist(const int* __restrict__ ei, int E, int N, int* __restrict__ deg){
  int e = blockIdx.x*blockDim.x + threadIdx.x;
  if (e >= E + N) return;
  int dst = (e < E) ? ei[E + e] : (e - E);
  atomicAdd(&deg[dst], 1);
}

// ---- 3-phase exclusive scan ----
__global__ void k_scanA(const int* __restrict__ deg, int* __restrict__ bsum, int N){
  __shared__ int sd[256];
  const int tid = threadIdx.x;
  const int base = blockIdx.x*1024 + tid*4;
  int s = 0;
#pragma unroll
  for (int j = 0; j < 4; j++){ int i = base + j; if (i < N) s += deg[i]; }
  sd[tid] = s; __syncthreads();
  for (int off = 128; off > 0; off >>= 1){
    if (tid < off) sd[tid] += sd[tid+off];
    __syncthreads();
  }
  if (tid == 0) bsum[blockIdx.x] = sd[0];
}

__global__ void k_scanB(const int* __restrict__ bsum, int* __restrict__ boff,
                        int* __restrict__ rowptrN, int NBLK){
  const int lane = threadIdx.x;   // 64 threads
  int carry = 0;
  for (int c = 0; c < NBLK; c += 64){
    int idx = c + lane;
    int v = (idx < NBLK) ? bsum[idx] : 0;
    int incl = v;
    for (int off = 1; off < 64; off <<= 1){
      int t = __shfl_up(incl, off);
      if (lane >= off) incl += t;
    }
    if (idx < NBLK) boff[idx] = carry + incl - v;
    carry += __shfl(incl, 63);
  }
  if (lane == 0) *rowptrN = carry;
}

__global__ void k_scanC(const int* __restrict__ deg, const int* __restrict__ boff,
                        int* __restrict__ rowptr, int* __restrict__ cursor, int N){
  __shared__ int ts[256];
  const int tid = threadIdx.x;
  const int base = blockIdx.x*1024 + tid*4;
  int v[4]; int s = 0;
#pragma unroll
  for (int j = 0; j < 4; j++){ int i = base + j; v[j] = (i < N) ? deg[i] : 0; s += v[j]; }
  ts[tid] = s; __syncthreads();
  for (int off = 1; off < 256; off <<= 1){
    int t = (tid >= off) ? ts[tid-off] : 0;
    __syncthreads();
    ts[tid] += t;
    __syncthreads();
  }
  int excl = ((tid > 0) ? ts[tid-1] : 0) + boff[blockIdx.x];
#pragma unroll
  for (int j = 0; j < 4; j++){
    int i = base + j;
    if (i < N){ rowptr[i] = excl; cursor[i] = excl; }
    excl += v[j];
  }
}

__global__ void k_fill(const int* __restrict__ ei, const int* __restrict__ ea,
                       int E, int N, int* __restrict__ cursor,
                       unsigned int* __restrict__ entries)
{
  int e = blockIdx.x*blockDim.x + threadIdx.x;
  if (e >= E + N) return;
  int src, dst, bt, bd;
  if (e < E) { src = ei[e]; dst = ei[E + e]; bt = ea[2*e]; bd = ea[2*e + 1]; }
  else       { src = e - E; dst = src;       bt = 4;       bd = 0; }
  int pos = atomicAdd(&cursor[dst], 1);
  entries[pos] = (unsigned)src | ((unsigned)bt << 20) | ((unsigned)bd << 24);
}

// W: [NLAYER][K][Ncol] f32 -> WT: [NLAYER][Np][Kp] f16 (transposed, zero-padded)
__global__ void k_prep_w(const float* __restrict__ W, f16* __restrict__ WT,
                         int K, int Ncol, int Kp, int Np)
{
  int i = blockIdx.x*blockDim.x + threadIdx.x;
  int total = NLAYER * Np * Kp;
  if (i >= total) return;
  int l = i / (Np * Kp);
  int rem = i - l * (Np * Kp);
  int n = rem / Kp;
  int k = rem - n * Kp;
  f16 v = (f16)0.f;
  if (n < Ncol && k < K) v = (f16)W[(size_t)l*K*Ncol + (size_t)k*Ncol + n];
  WT[i] = v;
}

// [R][SC] f32 -> [R][DC] f32 zero-padded
__global__ void k_padb(const float* __restrict__ src, float* __restrict__ dst,
                       int R, int SC, int DC)
{
  int i = blockIdx.x*blockDim.x + threadIdx.x;
  if (i >= R * DC) return;
  int r = i / DC, c = i - r * DC;
  dst[i] = (c < SC) ? src[r*SC + c] : 0.f;
}

// h0 f16 padded: h[n][c] = f16(xe1[x0][c] + xe2[x1][c])
__global__ void k_h0(const int* __restrict__ x, const float* __restrict__ xe1,
                     const float* __restrict__ xe2, f16* __restrict__ h, int N)
{
  const int w = threadIdx.x >> 6, lane = threadIdx.x & 63;
  const int n = blockIdx.x * 4 + w;
  if (n >= N || lane >= 40) return;
  const int c0 = lane * 8;
  const bool lo = (c0 + 4) <= EMB;
  const bool hi = (c0 + 8) <= EMB;
  const float* r1 = xe1 + (size_t)x[2*n]*EMB + c0;
  const float* r2 = xe2 + (size_t)x[2*n+1]*EMB + c0;
  f32x4 a1 = lo ? *(const f32x4*)r1     : (f32x4){0,0,0,0};
  f32x4 a2 = hi ? *(const f32x4*)(r1+4) : (f32x4){0,0,0,0};
  f32x4 b1 = lo ? *(const f32x4*)r2     : (f32x4){0,0,0,0};
  f32x4 b2 = hi ? *(const f32x4*)(r2+4) : (f32x4){0,0,0,0};
  hfrag o;
#pragma unroll
  for (int j = 0; j < 4; j++){
    o[j]   = (f16)(a1[j] + b1[j]);
    o[4+j] = (f16)(a2[j] + b2[j]);
  }
  *(hfrag*)&h[(size_t)n*EMBP + c0] = o;
}

// ---------------- aggregation: one wave per node, plain f16 gather ----------------
// 8-wide predicated batches (wave-uniform mask): 1 latency round for deg<=8 (~93%).
__global__ __launch_bounds__(256) void k_aggr(
    const f16* __restrict__ h,                  // [N][EMBP] f16 (pre-transformed)
    const int* __restrict__ rowptr,
    const unsigned int* __restrict__ entries,
    const float* __restrict__ t1,               // [6][EMBP] f32 padded
    const float* __restrict__ t2,               // [3][EMBP] f32 padded
    f16* __restrict__ aggr, int N, int Mp)
{
  const int w = threadIdx.x >> 6, lane = threadIdx.x & 63;
  const int n = blockIdx.x * 4 + w;
  if (n >= Mp || lane >= 40) return;
  const int c0 = lane * 8;
  float s[8] = {0.f,0.f,0.f,0.f,0.f,0.f,0.f,0.f};
  if (n < N) {
    const int beg = rowptr[n], end = rowptr[n+1];
    int c6[6] = {0,0,0,0,0,0};
    int c3[3] = {0,0,0};
    for (int b0 = beg; b0 < end; b0 += 8) {
      unsigned pe[8]; bool vl[8];
#pragma unroll
      for (int j = 0; j < 8; j++){
        const int idx = b0 + j;
        vl[j] = idx < end;                 // wave-uniform
        pe[j] = entries[vl[j] ? idx : beg];
      }
      hfrag v[8];
#pragma unroll
      for (int j = 0; j < 8; j++)
        v[j] = *(const hfrag*)&h[(size_t)(pe[j] & 0xFFFFF)*EMBP + c0];
#pragma unroll
      for (int j = 0; j < 8; j++){
        if (vl[j]){
          const int bt = (pe[j] >> 20) & 7, bd = (pe[j] >> 24) & 3;
#pragma unroll
          for (int t = 0; t < 6; t++) c6[t] += (bt == t);
#pragma unroll
          for (int t = 0; t < 3; t++) c3[t] += (bd == t);
#pragma unroll
          for (int k = 0; k < 8; k++) s[k] += (float)v[j][k];
        }
      }
    }
#pragma unroll
    for (int t = 0; t < 6; t++) if (c6[t]) {
      const float f = (float)c6[t];
      f32x4 a = *(const f32x4*)&t1[t*EMBP + c0];
      f32x4 b = *(const f32x4*)&t1[t*EMBP + c0 + 4];
#pragma unroll
      for (int k = 0; k < 4; k++){ s[k] += f*a[k]; s[4+k] += f*b[k]; }
    }
#pragma unroll
    for (int t = 0; t < 3; t++) if (c3[t]) {
      const float f = (float)c3[t];
      f32x4 a = *(const f32x4*)&t2[t*EMBP + c0];
      f32x4 b = *(const f32x4*)&t2[t*EMBP + c0 + 4];
#pragma unroll
      for (int k = 0; k < 4; k++){ s[k] += f*a[k]; s[4+k] += f*b[k]; }
    }
  }
  hfrag o;
#pragma unroll
  for (int j = 0; j < 8; j++) o[j] = (f16)s[j];
  *(hfrag*)&aggr[(size_t)n*EMBP + c0] = o;
}

// ---------------- GEMM: 128x128 tile, BK=32, dbuf + counted vmcnt, XCD-chunked ----
// MODE 0: C = f16 relu -> hid [*][HIDP], chunk-local rows, no stats.
// MODE 1: C = f16 -> outh [Mp][EMBP] (zero pad cols >= EMB), + fused BN stats.
// MODE 2: C = f32 -> dout [N][EMB] masked, + fused BN stats.
template<int KP, int NCT, int MODE>
__global__ __launch_bounds__(256) void k_gemm(
    const f16* __restrict__ A,
    const f16* __restrict__ Bt,
    const float* __restrict__ bias,
    void* __restrict__ Cv,
    float* __restrict__ part,
    int nBase, int N)
{
  constexpr int NT = KP / 32;
  __shared__ __align__(16) f16 As[2][128*32];
  __shared__ __align__(16) f16 Bs[2][128*32];
  __shared__ float redS[4][64];
  __shared__ float redQ[4][64];
  const int tid = threadIdx.x;
  const int w = tid >> 6, lane = tid & 63;
  const int wr = w >> 1, wc = w & 1;
  const int cl = lane & 15, kg = lane >> 4;

  // XCD-chunked decode (bijective, m204): col-tile fastest -> A-panel L2 reuse.
  const int nwg = gridDim.x;
  const int q = nwg >> 3, rr = nwg & 7;
  const int d = blockIdx.x;
  const int xc = d & 7, jj = d >> 3;
  const int wk = xc*q + (xc < rr ? xc : rr) + jj;
  const int m0 = (wk / NCT) * 128;
  const int n0 = (wk % NCT) * 128;

  // staging: 2 rounds x 256 threads cover 128 rows x 4 segs (16B each).
  // LDS dest linear; global source pre-swizzled seg_g = seg ^ ((row>>1)&3).
  const f16* ag[2]; const f16* bg[2]; int ldst[2];
#pragma unroll
  for (int i = 0; i < 2; i++){
    const int id = i*256 + tid;
    const int row = id >> 2, seg = id & 3;
    const int col = (seg ^ ((row >> 1) & 3)) * 8;
    ag[i] = A  + (size_t)(m0 + row)*KP + col;
    bg[i] = Bt + (size_t)(n0 + row)*KP + col;
    ldst[i] = id * 8;
  }

  auto STAGE = [&](int bb, int kt){
    const int k0 = kt*32;
#pragma unroll
    for (int i = 0; i < 2; i++) gload16(ag[i] + k0, &As[bb][ldst[i]]);
#pragma unroll
    for (int i = 0; i < 2; i++) gload16(bg[i] + k0, &Bs[bb][ldst[i]]);
  };

  f32x4 acc[4][4];
#pragma unroll
  for (int i = 0; i < 4; i++)
#pragma unroll
    for (int j = 0; j < 4; j++)
      acc[i][j] = (f32x4){0.f, 0.f, 0.f, 0.f};

  const int sw3 = (cl >> 1) & 3;   // (row>>1)&3 with row = base16 + cl

  STAGE(0, 0);
#pragma unroll 4
  for (int t = 0; t < NT; ++t){
    const int cur = t & 1;
    if (t + 1 < NT){
      STAGE(cur ^ 1, t + 1);                       // prefetch stays in flight
      asm volatile("s_waitcnt vmcnt(4)" ::: "memory");   // only tile t drained
    } else {
      asm volatile("s_waitcnt vmcnt(0)" ::: "memory");
    }
    __builtin_amdgcn_s_barrier();                  // raw: no full drain
    hfrag af[4], bf[4];
#pragma unroll
    for (int mf = 0; mf < 4; mf++)
      af[mf] = *(const hfrag*)&As[cur][(wr*64 + mf*16 + cl)*32 + ((kg ^ sw3) * 8)];
#pragma unroll
    for (int nf = 0; nf < 4; nf++)
      bf[nf] = *(const hfrag*)&Bs[cur][(wc*64 + nf*16 + cl)*32 + ((kg ^ sw3) * 8)];
#pragma unroll
    for (int mf = 0; mf < 4; mf++)
#pragma unroll
      for (int nf = 0; nf < 4; nf++)
        acc[mf][nf] = __builtin_amdgcn_mfma_f32_16x16x32_f16(af[mf], bf[nf], acc[mf][nf], 0, 0, 0);
    __builtin_amdgcn_s_barrier();                  // buf reads done before re-stage
  }

  const int rg = lane >> 4;
  float ps[4] = {0.f,0.f,0.f,0.f}, pq[4] = {0.f,0.f,0.f,0.f};
#pragma unroll
  for (int mf = 0; mf < 4; mf++) {
#pragma unroll
    for (int nf = 0; nf < 4; nf++) {
      const int col  = n0 + wc*64 + nf*16 + cl;
      const int row0 = m0 + wr*64 + mf*16 + rg*4;
      f32x4 v = acc[mf][nf];
      if (MODE == 0) {
        const float bv = bias[col];
#pragma unroll
        for (int r = 0; r < 4; r++)
          ((f16*)Cv)[(size_t)(row0 + r)*HIDP + col] = (f16)fmaxf(v[r] + bv, 0.f);
      } else if (MODE == 1) {
        const float bv = bias[col];
#pragma unroll
        for (int r = 0; r < 4; r++) {
          const int grow = nBase + row0 + r;
          const float o = v[r] + bv;
          if (col < EMBP)
            ((f16*)Cv)[(size_t)grow*EMBP + col] = (col < EMB) ? (f16)o : (f16)0.f;
          if (grow < N) { ps[nf] += o; pq[nf] += o*o; }
        }
      } else {
        const float bv = bias[col];
#pragma unroll
        for (int r = 0; r < 4; r++) {
          const int grow = nBase + row0 + r;
          if (grow < N) {
            const float o = v[r] + bv;
            if (col < EMB) ((float*)Cv)[(size_t)grow*EMB + col] = o;
            ps[nf] += o; pq[nf] += o*o;
          }
        }
      }
    }
  }

  if (MODE != 0) {
    // deterministic reduce: shfl tree over rg, LDS over wr, per-(panel,colblock)
#pragma unroll
    for (int nf = 0; nf < 4; nf++){
      float s1 = ps[nf], q1 = pq[nf];
      s1 += __shfl_xor(s1, 16); q1 += __shfl_xor(q1, 16);
      s1 += __shfl_xor(s1, 32); q1 += __shfl_xor(q1, 32);
      if (rg == 0){ redS[w][nf*16 + cl] = s1; redQ[w][nf*16 + cl] = q1; }
    }
    __syncthreads();
    if (w < 2 && lane < 16){
      const int gb = (nBase + m0) >> 7;
      float* pS = part + (size_t)gb * (2*EMBP);
#pragma unroll
      for (int nf = 0; nf < 4; nf++){
        const int lc  = nf*16 + lane;
        const int col = n0 + w*64 + nf*16 + lane;
        if (col < EMBP){
          pS[col]        = redS[w][lc] + redS[w+2][lc];
          pS[EMBP + col] = redQ[w][lc] + redQ[w+2][lc];
        }
      }
    }
  }
}

// ---------------- BN finalize (parallel: one block per column) ----------------

__global__ __launch_bounds__(256) void k_bnfin(
    const float* __restrict__ part,
    const float* __restrict__ gamma,
    const float* __restrict__ beta,
    float* __restrict__ scl, float* __restrict__ sft, int N, int RB)
{
  __shared__ float rs[256], rq[256];
  const int c = blockIdx.x;          // 0..EMBP-1
  const int t = threadIdx.x;
  float s = 0.f, q = 0.f;
  for (int gb = t; gb < RB; gb += 256){
    s += part[(size_t)gb*(2*EMBP) + c];
    q += part[(size_t)gb*(2*EMBP) + EMBP + c];
  }
  rs[t] = s; rq[t] = q; __syncthreads();
  for (int off = 128; off > 0; off >>= 1){
    if (t < off){ rs[t] += rs[t+off]; rq[t] += rq[t+off]; }
    __syncthreads();
  }
  if (t == 0){
    if (c < EMB){
      float mean = rs[0] / (float)N;
      float var  = fmaxf(rq[0] / (float)N - mean*mean, 0.f);
      float sc = gamma[c] * rsqrtf(var + BNEPS);
      scl[c] = sc;
      sft[c] = beta[c] - mean*sc;
    } else { scl[c] = 0.f; sft[c] = 0.f; }
  }
}

// mid layers: h[n][c0..c0+7] = f16(relu(outh*scl+sft)) once per node (no per-edge
// amplification — R11 lesson). outh f16 [Mp][EMBP] -> h f16 [N][EMBP].
__global__ void k_bnapply(const f16* __restrict__ outh,
                          const float* __restrict__ scl, const float* __restrict__ sft,
                          f16* __restrict__ h, int N)
{
  int i = blockIdx.x*blockDim.x + threadIdx.x;
  if (i >= N * (EMBP/8)) return;
  const int n = i / (EMBP/8);
  const int c0 = (i - n*(EMBP/8)) * 8;
  hfrag v = *(const hfrag*)&outh[(size_t)n*EMBP + c0];
  hfrag o;
#pragma unroll
  for (int j = 0; j < 8; j++){
    const int c = c0 + j;
    float xv = (c < EMB) ? fmaxf(fmaf((float)v[j], scl[c], sft[c]), 0.f) : 0.f;
    o[j] = (f16)xv;
  }
  *(hfrag*)&h[(size_t)n*EMBP + c0] = o;
}

// last layer: dout = dout*scl + sft (no relu), in place
__global__ void k_bnlast(float* __restrict__ out, const float* __restrict__ scl,
                         const float* __restrict__ sft, int N){
  int i = blockIdx.x*blockDim.x + threadIdx.x;
  if (i >= N*EMB) return;
  int c = i % EMB;
  out[i] = out[i]*scl[c] + sft[c];
}

// ---------------- host ----------------

extern "C" void kernel_launch(void* const* d_in, const int* in_sizes, int n_in,
                              void* d_out, int out_size, void* d_ws, size_t ws_size,
                              hipStream_t stream)
{
  (void)n_in; (void)out_size;
  const int* x  = (const int*)d_in[0];
  const int* ei = (const int*)d_in[1];
  const int* ea = (const int*)d_in[2];
  const float* xe1 = (const float*)d_in[3];
  const float* xe2 = (const float*)d_in[4];
  const float* ee1 = (const float*)d_in[5];
  const float* ee2 = (const float*)d_in[6];
  const float* W1  = (const float*)d_in[7];
  const float* b1  = (const float*)d_in[8];
  const float* W2  = (const float*)d_in[9];
  const float* b2  = (const float*)d_in[10];
  const float* gam = (const float*)d_in[11];
  const float* bet = (const float*)d_in[12];

  const int N  = in_sizes[0] / 2;
  const int E  = in_sizes[1] / 2;
  const int EN = E + N;
  const int Mp = ((N + 127) / 128) * 128;
  const int RB = Mp / 128;
  const int NBLK = (N + 1023) / 1024;

  float* dout = (float*)d_out;

  char* ws = (char*)d_ws;
  size_t off = 0;
  auto alloc = [&](size_t bytes){ size_t o = off; off = (off + bytes + 255) & ~(size_t)255; return o; };

  f16* h                 = (f16*)(ws + alloc((size_t)N*EMBP*2));
  f16* outh              = (f16*)(ws + alloc((size_t)Mp*EMBP*2));
  f16* aggr              = (f16*)(ws + alloc((size_t)Mp*EMBP*2));
  unsigned int*  entries = (unsigned int*)(ws + alloc((size_t)EN*4));
  int* rowptr            = (int*)(ws + alloc((size_t)(N+1)*4));
  int* cursor            = (int*)(ws + alloc((size_t)N*4));
  int* deg               = (int*)(ws + alloc((size_t)N*4));
  int* bsum              = (int*)(ws + alloc((size_t)NBLK*4));
  int* boff              = (int*)(ws + alloc((size_t)NBLK*4));
  f16* W1T               = (f16*)(ws + alloc((size_t)NLAYER*HIDP*EMBP*2));
  f16* W2T               = (f16*)(ws + alloc((size_t)NLAYER*EMBP2*HIDP*2));
  float* e1pf            = (float*)(ws + alloc((size_t)NLAYER*6*EMBP*4));
  float* e2pf            = (float*)(ws + alloc((size_t)NLAYER*3*EMBP*4));
  float* b1p             = (float*)(ws + alloc((size_t)NLAYER*HIDP*4));
  float* b2p             = (float*)(ws + alloc((size_t)NLAYER*EMBP*4));
  float* part            = (float*)(ws + alloc((size_t)RB*2*EMBP*4));
  float* scl             = (float*)(ws + alloc((size_t)EMBP*4));
  float* sft             = (float*)(ws + alloc((size_t)EMBP*4));

  if (off >= ws_size) return;
  size_t avail = ws_size - off;
  size_t maxrows = avail / ((size_t)HIDP*2);
  if (maxrows < 128) return;
  int CH = (maxrows >= (size_t)Mp) ? Mp : (int)(maxrows & ~(size_t)127);
  f16* hidc = (f16*)(ws + off);

  // CSR build
  k_zero<<<(N+255)/256, 256, 0, stream>>>((unsigned int*)deg, N);
  k_hist<<<(EN+255)/256, 256, 0, stream>>>(ei, E, N, deg);
  k_scanA<<<NBLK, 256, 0, stream>>>(deg, bsum, N);
  k_scanB<<<1, 64, 0, stream>>>(bsum, boff, rowptr + N, NBLK);
  k_scanC<<<NBLK, 256, 0, stream>>>(deg, boff, rowptr, cursor, N);
  k_fill<<<(EN+255)/256, 256, 0, stream>>>(ei, ea, E, N, cursor, entries);

  // weight/table prep
  {
    int tot1 = NLAYER*HIDP*EMBP;
    k_prep_w<<<(tot1+255)/256, 256, 0, stream>>>(W1, W1T, EMB, HID, EMBP, HIDP);
    int tot2 = NLAYER*EMBP2*HIDP;
    k_prep_w<<<(tot2+255)/256, 256, 0, stream>>>(W2, W2T, HID, EMB, HIDP, EMBP2);
  }
  k_padb<<<((NLAYER*6*EMBP)+255)/256, 256, 0, stream>>>(ee1, e1pf, NLAYER*6, EMB, EMBP);
  k_padb<<<((NLAYER*3*EMBP)+255)/256, 256, 0, stream>>>(ee2, e2pf, NLAYER*3, EMB, EMBP);
  k_padb<<<((NLAYER*HIDP)+255)/256, 256, 0, stream>>>(b1, b1p, NLAYER, HID, HIDP);
  k_padb<<<((NLAYER*EMBP)+255)/256, 256, 0, stream>>>(b2, b2p, NLAYER, EMB, EMBP);

  // h0 f16
  k_h0<<<(N+3)/4, 256, 0, stream>>>(x, xe1, xe2, h, N);

  for (int l = 0; l < NLAYER; ++l) {
    k_aggr<<<Mp/4, 256, 0, stream>>>(h, rowptr, entries,
        e1pf + (size_t)l*6*EMBP, e2pf + (size_t)l*3*EMBP, aggr, N, Mp);

    for (int base = 0; base < Mp; base += CH) {
      const int rows = (Mp - base < CH) ? (Mp - base) : CH;
      const int nwg1 = (rows/128) * (HIDP/128);
      k_gemm<EMBP, HIDP/128, 0><<<nwg1, 256, 0, stream>>>(
          aggr + (size_t)base*EMBP, W1T + (size_t)l*HIDP*EMBP,
          b1p + (size_t)l*HIDP, hidc, nullptr, base, N);
      const int nwg2 = (rows/128) * (EMBP2/128);
      if (l < NLAYER - 1)
        k_gemm<HIDP, EMBP2/128, 1><<<nwg2, 256, 0, stream>>>(
            hidc, W2T + (size_t)l*EMBP2*HIDP,
            b2p + (size_t)l*EMBP, outh, part, base, N);
      else
        k_gemm<HIDP, EMBP2/128, 2><<<nwg2, 256, 0, stream>>>(
            hidc, W2T + (size_t)l*EMBP2*HIDP,
            b2p + (size_t)l*EMBP, dout, part, base, N);
    }
    k_bnfin<<<EMBP, 256, 0, stream>>>(part, gam + (size_t)l*EMB, bet + (size_t)l*EMB, scl, sft, N, RB);
    if (l < NLAYER - 1) {
      int tot = N * (EMBP/8);
      k_bnapply<<<(tot+255)/256, 256, 0, stream>>>(outh, scl, sft, h, N);
    }
  }
  k_bnlast<<<((N*EMB)+255)/256, 256, 0, stream>>>(dout, scl, sft, N);
}

// Round 15
// 974.267 us; speedup vs baseline: 1.0170x; 1.0170x over previous
//
#include <hip/hip_runtime.h>
#include <stdint.h>

#define NLAYER 5
#define EMB    300
#define EMBP   320
#define EMBP2  384
#define HID    600
#define HIDP   640
#define BNEPS  1e-5f

typedef _Float16 f16;
typedef __attribute__((ext_vector_type(8))) _Float16 hfrag;
typedef __attribute__((ext_vector_type(4))) float f32x4;

__device__ __forceinline__ void gload16(const void* g, void* l){
  __builtin_amdgcn_global_load_lds(
      (const __attribute__((address_space(1))) void*)g,
      (__attribute__((address_space(3))) void*)l,
      16, 0, 0);
}

// ---------------- setup kernels ----------------

__global__ void k_zero(unsigned int* __restrict__ p, int n){
  int i = blockIdx.x*blockDim.x + threadIdx.x;
  if (i < n) p[i] = 0u;
}

__global__ void k_hist(const int* __restrict__ ei, int E, int N, int* __restrict__ deg){
  int e = blockIdx.x*blockDim.x + threadIdx.x;
  if (e >= E + N) return;
  int dst = (e < E) ? ei[E + e] : (e - E);
  atomicAdd(&deg[dst], 1);
}

// ---- 3-phase exclusive scan ----
__global__ void k_scanA(const int* __restrict__ deg, int* __restrict__ bsum, int N){
  __shared__ int sd[256];
  const int tid = threadIdx.x;
  const int base = blockIdx.x*1024 + tid*4;
  int s = 0;
#pragma unroll
  for (int j = 0; j < 4; j++){ int i = base + j; if (i < N) s += deg[i]; }
  sd[tid] = s; __syncthreads();
  for (int off = 128; off > 0; off >>= 1){
    if (tid < off) sd[tid] += sd[tid+off];
    __syncthreads();
  }
  if (tid == 0) bsum[blockIdx.x] = sd[0];
}

__global__ void k_scanB(const int* __restrict__ bsum, int* __restrict__ boff,
                        int* __restrict__ rowptrN, int NBLK){
  const int lane = threadIdx.x;   // 64 threads
  int carry = 0;
  for (int c = 0; c < NBLK; c += 64){
    int idx = c + lane;
    int v = (idx < NBLK) ? bsum[idx] : 0;
    int incl = v;
    for (int off = 1; off < 64; off <<= 1){
      int t = __shfl_up(incl, off);
      if (lane >= off) incl += t;
    }
    if (idx < NBLK) boff[idx] = carry + incl - v;
    carry += __shfl(incl, 63);
  }
  if (lane == 0) *rowptrN = carry;
}

__global__ void k_scanC(const int* __restrict__ deg, const int* __restrict__ boff,
                        int* __restrict__ rowptr, int* __restrict__ cursor, int N){
  __shared__ int ts[256];
  const int tid = threadIdx.x;
  const int base = blockIdx.x*1024 + tid*4;
  int v[4]; int s = 0;
#pragma unroll
  for (int j = 0; j < 4; j++){ int i = base + j; v[j] = (i < N) ? deg[i] : 0; s += v[j]; }
  ts[tid] = s; __syncthreads();
  for (int off = 1; off < 256; off <<= 1){
    int t = (tid >= off) ? ts[tid-off] : 0;
    __syncthreads();
    ts[tid] += t;
    __syncthreads();
  }
  int excl = ((tid > 0) ? ts[tid-1] : 0) + boff[blockIdx.x];
#pragma unroll
  for (int j = 0; j < 4; j++){
    int i = base + j;
    if (i < N){ rowptr[i] = excl; cursor[i] = excl; }
    excl += v[j];
  }
}

__global__ void k_fill(const int* __restrict__ ei, const int* __restrict__ ea,
                       int E, int N, int* __restrict__ cursor,
                       unsigned int* __restrict__ entries)
{
  int e = blockIdx.x*blockDim.x + threadIdx.x;
  if (e >= E + N) return;
  int src, dst, bt, bd;
  if (e < E) { src = ei[e]; dst = ei[E + e]; bt = ea[2*e]; bd = ea[2*e + 1]; }
  else       { src = e - E; dst = src;       bt = 4;       bd = 0; }
  int pos = atomicAdd(&cursor[dst], 1);
  entries[pos] = (unsigned)src | ((unsigned)bt << 20) | ((unsigned)bd << 24);
}

// single consolidated prep: W1T, W2T (transpose+pad f16), e1pf/e2pf/b1p/b2p (pad f32)
__global__ void k_prep(const float* __restrict__ W1, const float* __restrict__ W2,
                       const float* __restrict__ ee1, const float* __restrict__ ee2,
                       const float* __restrict__ b1, const float* __restrict__ b2,
                       f16* __restrict__ W1T, f16* __restrict__ W2T,
                       float* __restrict__ e1pf, float* __restrict__ e2pf,
                       float* __restrict__ b1p, float* __restrict__ b2p)
{
  int i = blockIdx.x*blockDim.x + threadIdx.x;
  const int t1 = NLAYER*HIDP*EMBP;
  const int t2 = NLAYER*EMBP2*HIDP;
  const int t3 = NLAYER*6*EMBP;
  const int t4 = NLAYER*3*EMBP;
  const int t5 = NLAYER*HIDP;
  const int t6 = NLAYER*EMBP;
  if (i < t1){
    int l = i/(HIDP*EMBP), rem = i - l*(HIDP*EMBP);
    int n = rem/EMBP, k = rem - n*EMBP;
    f16 v = (f16)0.f;
    if (n < HID && k < EMB) v = (f16)W1[((size_t)l*EMB + k)*HID + n];
    W1T[i] = v; return;
  }
  i -= t1;
  if (i < t2){
    int l = i/(EMBP2*HIDP), rem = i - l*(EMBP2*HIDP);
    int n = rem/HIDP, k = rem - n*HIDP;
    f16 v = (f16)0.f;
    if (n < EMB && k < HID) v = (f16)W2[((size_t)l*HID + k)*EMB + n];
    W2T[i] = v; return;
  }
  i -= t2;
  if (i < t3){
    int r = i/EMBP, c = i - r*EMBP;
    e1pf[i] = (c < EMB) ? ee1[r*EMB + c] : 0.f; return;
  }
  i -= t3;
  if (i < t4){
    int r = i/EMBP, c = i - r*EMBP;
    e2pf[i] = (c < EMB) ? ee2[r*EMB + c] : 0.f; return;
  }
  i -= t4;
  if (i < t5){
    int r = i/HIDP, c = i - r*HIDP;
    b1p[i] = (c < HID) ? b1[r*HID + c] : 0.f; return;
  }
  i -= t5;
  if (i < t6){
    int r = i/EMBP, c = i - r*EMBP;
    b2p[i] = (c < EMB) ? b2[r*EMB + c] : 0.f; return;
  }
}

// h0 f16 padded into hb: hb[n][c] = f16(xe1[x0][c] + xe2[x1][c])
__global__ void k_h0(const int* __restrict__ x, const float* __restrict__ xe1,
                     const float* __restrict__ xe2, f16* __restrict__ hb, int N)
{
  const int w = threadIdx.x >> 6, lane = threadIdx.x & 63;
  const int n = blockIdx.x * 4 + w;
  if (n >= N || lane >= 40) return;
  const int c0 = lane * 8;
  const bool lo = (c0 + 4) <= EMB;
  const bool hi = (c0 + 8) <= EMB;
  const float* r1 = xe1 + (size_t)x[2*n]*EMB + c0;
  const float* r2 = xe2 + (size_t)x[2*n+1]*EMB + c0;
  f32x4 a1 = lo ? *(const f32x4*)r1     : (f32x4){0,0,0,0};
  f32x4 a2 = hi ? *(const f32x4*)(r1+4) : (f32x4){0,0,0,0};
  f32x4 b1 = lo ? *(const f32x4*)r2     : (f32x4){0,0,0,0};
  f32x4 b2 = hi ? *(const f32x4*)(r2+4) : (f32x4){0,0,0,0};
  hfrag o;
#pragma unroll
  for (int j = 0; j < 4; j++){
    o[j]   = (f16)(a1[j] + b1[j]);
    o[4+j] = (f16)(a2[j] + b2[j]);
  }
  *(hfrag*)&hb[(size_t)n*EMBP + c0] = o;
}

// ---------------- aggregation: one wave per node, plain f16 gather ----------------
__global__ __launch_bounds__(256) void k_aggr(
    const f16* __restrict__ h,                  // [*][EMBP] f16 (pre-transformed)
    const int* __restrict__ rowptr,
    const unsigned int* __restrict__ entries,
    const float* __restrict__ t1,               // [6][EMBP] f32 padded
    const float* __restrict__ t2,               // [3][EMBP] f32 padded
    f16* __restrict__ aggr, int N, int Mp)
{
  const int w = threadIdx.x >> 6, lane = threadIdx.x & 63;
  const int n = blockIdx.x * 4 + w;
  if (n >= Mp || lane >= 40) return;
  const int c0 = lane * 8;
  float s[8] = {0.f,0.f,0.f,0.f,0.f,0.f,0.f,0.f};
  if (n < N) {
    const int beg = rowptr[n], end = rowptr[n+1];
    int c6[6] = {0,0,0,0,0,0};
    int c3[3] = {0,0,0};
    for (int b0 = beg; b0 < end; b0 += 8) {
      unsigned pe[8]; bool vl[8];
#pragma unroll
      for (int j = 0; j < 8; j++){
        const int idx = b0 + j;
        vl[j] = idx < end;                 // wave-uniform
        pe[j] = entries[vl[j] ? idx : beg];
      }
      hfrag v[8];
#pragma unroll
      for (int j = 0; j < 8; j++)
        v[j] = *(const hfrag*)&h[(size_t)(pe[j] & 0xFFFFF)*EMBP + c0];
#pragma unroll
      for (int j = 0; j < 8; j++){
        if (vl[j]){
          const int bt = (pe[j] >> 20) & 7, bd = (pe[j] >> 24) & 3;
#pragma unroll
          for (int t = 0; t < 6; t++) c6[t] += (bt == t);
#pragma unroll
          for (int t = 0; t < 3; t++) c3[t] += (bd == t);
#pragma unroll
          for (int k = 0; k < 8; k++) s[k] += (float)v[j][k];
        }
      }
    }
#pragma unroll
    for (int t = 0; t < 6; t++) if (c6[t]) {
      const float f = (float)c6[t];
      f32x4 a = *(const f32x4*)&t1[t*EMBP + c0];
      f32x4 b = *(const f32x4*)&t1[t*EMBP + c0 + 4];
#pragma unroll
      for (int k = 0; k < 4; k++){ s[k] += f*a[k]; s[4+k] += f*b[k]; }
    }
#pragma unroll
    for (int t = 0; t < 3; t++) if (c3[t]) {
      const float f = (float)c3[t];
      f32x4 a = *(const f32x4*)&t2[t*EMBP + c0];
      f32x4 b = *(const f32x4*)&t2[t*EMBP + c0 + 4];
#pragma unroll
      for (int k = 0; k < 4; k++){ s[k] += f*a[k]; s[4+k] += f*b[k]; }
    }
  }
  hfrag o;
#pragma unroll
  for (int j = 0; j < 8; j++) o[j] = (f16)s[j];
  *(hfrag*)&aggr[(size_t)n*EMBP + c0] = o;
}

// ---------------- GEMM: 128x128 tile, BK=32, R12-exact 2-stage dbuf, XCD-chunked ----
// MODE 0: C = f16 relu -> hid [*][HIDP], chunk-local rows, no stats.
// MODE 1: C = f16 -> hb [Mp][EMBP] (zero pad cols >= EMB), + fused BN stats.
template<int KP, int NCT, int MODE>
__global__ __launch_bounds__(256) void k_gemm(
    const f16* __restrict__ A,
    const f16* __restrict__ Bt,
    const float* __restrict__ bias,
    void* __restrict__ Cv,
    float* __restrict__ part,
    int nBase, int N)
{
  constexpr int NT = KP / 32;
  __shared__ __align__(16) f16 As[2][128*32];
  __shared__ __align__(16) f16 Bs[2][128*32];
  __shared__ float redS[4][64];
  __shared__ float redQ[4][64];
  const int tid = threadIdx.x;
  const int w = tid >> 6, lane = tid & 63;
  const int wr = w >> 1, wc = w & 1;
  const int cl = lane & 15, kg = lane >> 4;

  // XCD-chunked decode (bijective, m204): col-tile fastest -> A-panel L2 reuse.
  const int nwg = gridDim.x;
  const int q = nwg >> 3, rr = nwg & 7;
  const int d = blockIdx.x;
  const int xc = d & 7, jj = d >> 3;
  const int wk = xc*q + (xc < rr ? xc : rr) + jj;
  const int m0 = (wk / NCT) * 128;
  const int n0 = (wk % NCT) * 128;

  // staging: 2 rounds x 256 threads cover 128 rows x 4 segs (16B each).
  // LDS dest linear; global source pre-swizzled seg_g = seg ^ ((row>>1)&3).
  const f16* ag[2]; const f16* bg[2]; int ldst[2];
#pragma unroll
  for (int i = 0; i < 2; i++){
    const int id = i*256 + tid;
    const int row = id >> 2, seg = id & 3;
    const int col = (seg ^ ((row >> 1) & 3)) * 8;
    ag[i] = A  + (size_t)(m0 + row)*KP + col;
    bg[i] = Bt + (size_t)(n0 + row)*KP + col;
    ldst[i] = id * 8;
  }

  auto STAGE = [&](int bb, int kt){
    const int k0 = kt*32;
#pragma unroll
    for (int i = 0; i < 2; i++) gload16(ag[i] + k0, &As[bb][ldst[i]]);
#pragma unroll
    for (int i = 0; i < 2; i++) gload16(bg[i] + k0, &Bs[bb][ldst[i]]);
  };

  f32x4 acc[4][4];
#pragma unroll
  for (int i = 0; i < 4; i++)
#pragma unroll
    for (int j = 0; j < 4; j++)
      acc[i][j] = (f32x4){0.f, 0.f, 0.f, 0.f};

  const int sw3 = (cl >> 1) & 3;   // (row>>1)&3 with row = base16 + cl

  STAGE(0, 0);
#pragma unroll 4
  for (int t = 0; t < NT; ++t){
    const int cur = t & 1;
    if (t + 1 < NT){
      STAGE(cur ^ 1, t + 1);                       // prefetch stays in flight
      asm volatile("s_waitcnt vmcnt(4)" ::: "memory");   // only tile t drained
    } else {
      asm volatile("s_waitcnt vmcnt(0)" ::: "memory");
    }
    __builtin_amdgcn_s_barrier();                  // raw: no full drain
    hfrag af[4], bf[4];
#pragma unroll
    for (int mf = 0; mf < 4; mf++)
      af[mf] = *(const hfrag*)&As[cur][(wr*64 + mf*16 + cl)*32 + ((kg ^ sw3) * 8)];
#pragma unroll
    for (int nf = 0; nf < 4; nf++)
      bf[nf] = *(const hfrag*)&Bs[cur][(wc*64 + nf*16 + cl)*32 + ((kg ^ sw3) * 8)];
#pragma unroll
    for (int mf = 0; mf < 4; mf++)
#pragma unroll
      for (int nf = 0; nf < 4; nf++)
        acc[mf][nf] = __builtin_amdgcn_mfma_f32_16x16x32_f16(af[mf], bf[nf], acc[mf][nf], 0, 0, 0);
    __builtin_amdgcn_s_barrier();                  // buf reads done before re-stage
  }

  const int rg = lane >> 4;
  float ps[4] = {0.f,0.f,0.f,0.f}, pq[4] = {0.f,0.f,0.f,0.f};
#pragma unroll
  for (int mf = 0; mf < 4; mf++) {
#pragma unroll
    for (int nf = 0; nf < 4; nf++) {
      const int col  = n0 + wc*64 + nf*16 + cl;
      const int row0 = m0 + wr*64 + mf*16 + rg*4;
      f32x4 v = acc[mf][nf];
      if (MODE == 0) {
        const float bv = bias[col];
#pragma unroll
        for (int r = 0; r < 4; r++)
          ((f16*)Cv)[(size_t)(row0 + r)*HIDP + col] = (f16)fmaxf(v[r] + bv, 0.f);
      } else {
        const float bv = bias[col];
#pragma unroll
        for (int r = 0; r < 4; r++) {
          const int grow = nBase + row0 + r;
          const float o = v[r] + bv;
          if (col < EMBP)
            ((f16*)Cv)[(size_t)grow*EMBP + col] = (col < EMB) ? (f16)o : (f16)0.f;
          if (grow < N) { ps[nf] += o; pq[nf] += o*o; }
        }
      }
    }
  }

  if (MODE != 0) {
    // deterministic reduce: shfl tree over rg, LDS over wr, per-(panel,colblock)
#pragma unroll
    for (int nf = 0; nf < 4; nf++){
      float s1 = ps[nf], q1 = pq[nf];
      s1 += __shfl_xor(s1, 16); q1 += __shfl_xor(q1, 16);
      s1 += __shfl_xor(s1, 32); q1 += __shfl_xor(q1, 32);
      if (rg == 0){ redS[w][nf*16 + cl] = s1; redQ[w][nf*16 + cl] = q1; }
    }
    __syncthreads();
    if (w < 2 && lane < 16){
      const int gb = (nBase + m0) >> 7;
      float* pS = part + (size_t)gb * (2*EMBP);
#pragma unroll
      for (int nf = 0; nf < 4; nf++){
        const int lc  = nf*16 + lane;
        const int col = n0 + w*64 + nf*16 + lane;
        if (col < EMBP){
          pS[col]        = redS[w][lc] + redS[w+2][lc];
          pS[EMBP + col] = redQ[w][lc] + redQ[w+2][lc];
        }
      }
    }
  }
}

// ---------------- BN finalize (parallel: one block per column) ----------------

__global__ __launch_bounds__(256) void k_bnfin(
    const float* __restrict__ part,
    const float* __restrict__ gamma,
    const float* __restrict__ beta,
    float* __restrict__ scl, float* __restrict__ sft, int N, int RB)
{
  __shared__ float rs[256], rq[256];
  const int c = blockIdx.x;          // 0..EMBP-1
  const int t = threadIdx.x;
  float s = 0.f, q = 0.f;
  for (int gb = t; gb < RB; gb += 256){
    s += part[(size_t)gb*(2*EMBP) + c];
    q += part[(size_t)gb*(2*EMBP) + EMBP + c];
  }
  rs[t] = s; rq[t] = q; __syncthreads();
  for (int off = 128; off > 0; off >>= 1){
    if (t < off){ rs[t] += rs[t+off]; rq[t] += rq[t+off]; }
    __syncthreads();
  }
  if (t == 0){
    if (c < EMB){
      float mean = rs[0] / (float)N;
      float var  = fmaxf(rq[0] / (float)N - mean*mean, 0.f);
      float sc = gamma[c] * rsqrtf(var + BNEPS);
      scl[c] = sc;
      sft[c] = beta[c] - mean*sc;
    } else { scl[c] = 0.f; sft[c] = 0.f; }
  }
}

// mid layers: hb[n][c0..7] = f16(relu(hb*scl+sft)) IN PLACE (elementwise safe)
__global__ void k_bnapply(f16* __restrict__ hb,
                          const float* __restrict__ scl, const float* __restrict__ sft,
                          int N)
{
  int i = blockIdx.x*blockDim.x + threadIdx.x;
  if (i >= N * (EMBP/8)) return;
  const int n = i / (EMBP/8);
  const int c0 = (i - n*(EMBP/8)) * 8;
  hfrag v = *(const hfrag*)&hb[(size_t)n*EMBP + c0];
  hfrag o;
#pragma unroll
  for (int j = 0; j < 8; j++){
    const int c = c0 + j;
    float xv = (c < EMB) ? fmaxf(fmaf((float)v[j], scl[c], sft[c]), 0.f) : 0.f;
    o[j] = (f16)xv;
  }
  *(hfrag*)&hb[(size_t)n*EMBP + c0] = o;
}

// last layer: dout[n][c] = f32(hb[n][c])*scl + sft (no relu)
__global__ void k_bnlast(const f16* __restrict__ hb,
                         const float* __restrict__ scl, const float* __restrict__ sft,
                         float* __restrict__ out, int N){
  int i = blockIdx.x*blockDim.x + threadIdx.x;
  if (i >= N*EMB) return;
  int n = i / EMB, c = i - n*EMB;
  out[i] = (float)hb[(size_t)n*EMBP + c]*scl[c] + sft[c];
}

// ---------------- host ----------------

extern "C" void kernel_launch(void* const* d_in, const int* in_sizes, int n_in,
                              void* d_out, int out_size, void* d_ws, size_t ws_size,
                              hipStream_t stream)
{
  (void)n_in; (void)out_size;
  const int* x  = (const int*)d_in[0];
  const int* ei = (const int*)d_in[1];
  const int* ea = (const int*)d_in[2];
  const float* xe1 = (const float*)d_in[3];
  const float* xe2 = (const float*)d_in[4];
  const float* ee1 = (const float*)d_in[5];
  const float* ee2 = (const float*)d_in[6];
  const float* W1  = (const float*)d_in[7];
  const float* b1  = (const float*)d_in[8];
  const float* W2  = (const float*)d_in[9];
  const float* b2  = (const float*)d_in[10];
  const float* gam = (const float*)d_in[11];
  const float* bet = (const float*)d_in[12];

  const int N  = in_sizes[0] / 2;
  const int E  = in_sizes[1] / 2;
  const int EN = E + N;
  const int Mp = ((N + 127) / 128) * 128;
  const int RB = Mp / 128;
  const int NBLK = (N + 1023) / 1024;

  float* dout = (float*)d_out;

  char* ws = (char*)d_ws;
  size_t off = 0;
  auto alloc = [&](size_t bytes){ size_t o = off; off = (off + bytes + 255) & ~(size_t)255; return o; };

  f16* hb                = (f16*)(ws + alloc((size_t)Mp*EMBP*2));   // h & out (in-place BN)
  f16* aggrb             = (f16*)(ws + alloc((size_t)Mp*EMBP*2));
  unsigned int*  entries = (unsigned int*)(ws + alloc((size_t)EN*4));
  int* rowptr            = (int*)(ws + alloc((size_t)(N+1)*4));
  int* cursor            = (int*)(ws + alloc((size_t)N*4));
  int* deg               = (int*)(ws + alloc((size_t)N*4));
  int* bsum              = (int*)(ws + alloc((size_t)NBLK*4));
  int* boff              = (int*)(ws + alloc((size_t)NBLK*4));
  f16* W1T               = (f16*)(ws + alloc((size_t)NLAYER*HIDP*EMBP*2));
  f16* W2T               = (f16*)(ws + alloc((size_t)NLAYER*EMBP2*HIDP*2));
  float* e1pf            = (float*)(ws + alloc((size_t)NLAYER*6*EMBP*4));
  float* e2pf            = (float*)(ws + alloc((size_t)NLAYER*3*EMBP*4));
  float* b1p             = (float*)(ws + alloc((size_t)NLAYER*HIDP*4));
  float* b2p             = (float*)(ws + alloc((size_t)NLAYER*EMBP*4));
  float* part            = (float*)(ws + alloc((size_t)RB*2*EMBP*4));
  float* scl             = (float*)(ws + alloc((size_t)EMBP*4));
  float* sft             = (float*)(ws + alloc((size_t)EMBP*4));

  if (off >= ws_size) return;
  size_t avail = ws_size - off;
  size_t maxrows = avail / ((size_t)HIDP*2);
  if (maxrows < 128) return;
  int CH = (maxrows >= (size_t)Mp) ? Mp : (int)(maxrows & ~(size_t)127);
  f16* hidc = (f16*)(ws + off);

  // CSR build
  k_zero<<<(N+255)/256, 256, 0, stream>>>((unsigned int*)deg, N);
  k_hist<<<(EN+255)/256, 256, 0, stream>>>(ei, E, N, deg);
  k_scanA<<<NBLK, 256, 0, stream>>>(deg, bsum, N);
  k_scanB<<<1, 64, 0, stream>>>(bsum, boff, rowptr + N, NBLK);
  k_scanC<<<NBLK, 256, 0, stream>>>(deg, boff, rowptr, cursor, N);
  k_fill<<<(EN+255)/256, 256, 0, stream>>>(ei, ea, E, N, cursor, entries);

  // consolidated weight/table prep (1 launch)
  {
    int tot = NLAYER*HIDP*EMBP + NLAYER*EMBP2*HIDP + NLAYER*6*EMBP
            + NLAYER*3*EMBP + NLAYER*HIDP + NLAYER*EMBP;
    k_prep<<<(tot+255)/256, 256, 0, stream>>>(W1, W2, ee1, ee2, b1, b2,
                                              W1T, W2T, e1pf, e2pf, b1p, b2p);
  }

  // h0 f16 into hb
  k_h0<<<(N+3)/4, 256, 0, stream>>>(x, xe1, xe2, hb, N);

  for (int l = 0; l < NLAYER; ++l) {
    k_aggr<<<Mp/4, 256, 0, stream>>>(hb, rowptr, entries,
        e1pf + (size_t)l*6*EMBP, e2pf + (size_t)l*3*EMBP, aggrb, N, Mp);

    for (int base = 0; base < Mp; base += CH) {
      const int rows = (Mp - base < CH) ? (Mp - base) : CH;
      const int nwg1 = (rows/128) * (HIDP/128);
      k_gemm<EMBP, HIDP/128, 0><<<nwg1, 256, 0, stream>>>(
          aggrb + (size_t)base*EMBP, W1T + (size_t)l*HIDP*EMBP,
          b1p + (size_t)l*HIDP, hidc, nullptr, base, N);
      const int nwg2 = (rows/128) * (EMBP2/128);
      k_gemm<HIDP, EMBP2/128, 1><<<nwg2, 256, 0, stream>>>(
          hidc, W2T + (size_t)l*EMBP2*HIDP,
          b2p + (size_t)l*EMBP, hb, part, base, N);
    }
    k_bnfin<<<EMBP, 256, 0, stream>>>(part, gam + (size_t)l*EMB, bet + (size_t)l*EMB, scl, sft, N, RB);
    if (l < NLAYER - 1) {
      int tot = N * (EMBP/8);
      k_bnapply<<<(tot+255)/256, 256, 0, stream>>>(hb, scl, sft, N);
    }
  }
  k_bnlast<<<((N*EMB)+255)/256, 256, 0, stream>>>(hb, scl, sft, dout, N);
}

// Round 19
// 957.909 us; speedup vs baseline: 1.0343x; 1.0171x over previous
//
#include <hip/hip_runtime.h>
#include <stdint.h>

#define NLAYER 5
#define EMB    300
#define EMBP   320
#define EMBP2  384
#define HID    600
#define HIDP   640
#define BNEPS  1e-5f

typedef _Float16 f16;
typedef __attribute__((ext_vector_type(8))) _Float16 hfrag;
typedef __attribute__((ext_vector_type(4))) float f32x4;

__device__ __forceinline__ void gload16(const void* g, void* l){
  __builtin_amdgcn_global_load_lds(
      (const __attribute__((address_space(1))) void*)g,
      (__attribute__((address_space(3))) void*)l,
      16, 0, 0);
}

// ---------------- setup kernels ----------------

__global__ void k_zero(unsigned int* __restrict__ p, int n){
  int i = blockIdx.x*blockDim.x + threadIdx.x;
  if (i < n) p[i] = 0u;
}

__global__ void k_hist(const int* __restrict__ ei, int E, int N, int* __restrict__ deg){
  int e = blockIdx.x*blockDim.x + threadIdx.x;
  if (e >= E + N) return;
  int dst = (e < E) ? ei[E + e] : (e - E);
  atomicAdd(&deg[dst], 1);
}

// ---- 3-phase exclusive scan ----
__global__ void k_scanA(const int* __restrict__ deg, int* __restrict__ bsum, int N){
  __shared__ int sd[256];
  const int tid = threadIdx.x;
  const int base = blockIdx.x*1024 + tid*4;
  int s = 0;
#pragma unroll
  for (int j = 0; j < 4; j++){ int i = base + j; if (i < N) s += deg[i]; }
  sd[tid] = s; __syncthreads();
  for (int off = 128; off > 0; off >>= 1){
    if (tid < off) sd[tid] += sd[tid+off];
    __syncthreads();
  }
  if (tid == 0) bsum[blockIdx.x] = sd[0];
}

__global__ void k_scanB(const int* __restrict__ bsum, int* __restrict__ boff,
                        int* __restrict__ rowptrN, int NBLK){
  const int lane = threadIdx.x;   // 64 threads
  int carry = 0;
  for (int c = 0; c < NBLK; c += 64){
    int idx = c + lane;
    int v = (idx < NBLK) ? bsum[idx] : 0;
    int incl = v;
    for (int off = 1; off < 64; off <<= 1){
      int t = __shfl_up(incl, off);
      if (lane >= off) incl += t;
    }
    if (idx < NBLK) boff[idx] = carry + incl - v;
    carry += __shfl(incl, 63);
  }
  if (lane == 0) *rowptrN = carry;
}

__global__ void k_scanC(const int* __restrict__ deg, const int* __restrict__ boff,
                        int* __restrict__ rowptr, int* __restrict__ cursor, int N){
  __shared__ int ts[256];
  const int tid = threadIdx.x;
  const int base = blockIdx.x*1024 + tid*4;
  int v[4]; int s = 0;
#pragma unroll
  for (int j = 0; j < 4; j++){ int i = base + j; v[j] = (i < N) ? deg[i] : 0; s += v[j]; }
  ts[tid] = s; __syncthreads();
  for (int off = 1; off < 256; off <<= 1){
    int t = (tid >= off) ? ts[tid-off] : 0;
    __syncthreads();
    ts[tid] += t;
    __syncthreads();
  }
  int excl = ((tid > 0) ? ts[tid-1] : 0) + boff[blockIdx.x];
#pragma unroll
  for (int j = 0; j < 4; j++){
    int i = base + j;
    if (i < N){ rowptr[i] = excl; cursor[i] = excl; }
    excl += v[j];
  }
}

__global__ void k_fill(const int* __restrict__ ei, const int* __restrict__ ea,
                       int E, int N, int* __restrict__ cursor,
                       unsigned int* __restrict__ entries)
{
  int e = blockIdx.x*blockDim.x + threadIdx.x;
  if (e >= E + N) return;
  int src, dst, bt, bd;
  if (e < E) { src = ei[e]; dst = ei[E + e]; bt = ea[2*e]; bd = ea[2*e + 1]; }
  else       { src = e - E; dst = src;       bt = 4;       bd = 0; }
  int pos = atomicAdd(&cursor[dst], 1);
  entries[pos] = (unsigned)src | ((unsigned)bt << 20) | ((unsigned)bd << 24);
}

// single consolidated prep: W1T, W2T (transpose+pad f16), e1pf/e2pf/b1p/b2p (pad f32)
__global__ void k_prep(const float* __restrict__ W1, const float* __restrict__ W2,
                       const float* __restrict__ ee1, const float* __restrict__ ee2,
                       const float* __restrict__ b1, const float* __restrict__ b2,
                       f16* __restrict__ W1T, f16* __restrict__ W2T,
                       float* __restrict__ e1pf, float* __restrict__ e2pf,
                       float* __restrict__ b1p, float* __restrict__ b2p)
{
  int i = blockIdx.x*blockDim.x + threadIdx.x;
  const int t1 = NLAYER*HIDP*EMBP;
  const int t2 = NLAYER*EMBP2*HIDP;
  const int t3 = NLAYER*6*EMBP;
  const int t4 = NLAYER*3*EMBP;
  const int t5 = NLAYER*HIDP;
  const int t6 = NLAYER*EMBP;
  if (i < t1){
    int l = i/(HIDP*EMBP), rem = i - l*(HIDP*EMBP);
    int n = rem/EMBP, k = rem - n*EMBP;
    f16 v = (f16)0.f;
    if (n < HID && k < EMB) v = (f16)W1[((size_t)l*EMB + k)*HID + n];
    W1T[i] = v; return;
  }
  i -= t1;
  if (i < t2){
    int l = i/(EMBP2*HIDP), rem = i - l*(EMBP2*HIDP);
    int n = rem/HIDP, k = rem - n*HIDP;
    f16 v = (f16)0.f;
    if (n < EMB && k < HID) v = (f16)W2[((size_t)l*HID + k)*EMB + n];
    W2T[i] = v; return;
  }
  i -= t2;
  if (i < t3){
    int r = i/EMBP, c = i - r*EMBP;
    e1pf[i] = (c < EMB) ? ee1[r*EMB + c] : 0.f; return;
  }
  i -= t3;
  if (i < t4){
    int r = i/EMBP, c = i - r*EMBP;
    e2pf[i] = (c < EMB) ? ee2[r*EMB + c] : 0.f; return;
  }
  i -= t4;
  if (i < t5){
    int r = i/HIDP, c = i - r*HIDP;
    b1p[i] = (c < HID) ? b1[r*HID + c] : 0.f; return;
  }
  i -= t5;
  if (i < t6){
    int r = i/EMBP, c = i - r*EMBP;
    b2p[i] = (c < EMB) ? b2[r*EMB + c] : 0.f; return;
  }
}

// h0 f16 padded into hb; full-lane indexing: thread = node*40 + l40
__global__ void k_h0(const int* __restrict__ x, const float* __restrict__ xe1,
                     const float* __restrict__ xe2, f16* __restrict__ hb, int N)
{
  int gt = blockIdx.x*blockDim.x + threadIdx.x;
  int n = gt / 40;
  if (n >= N) return;
  const int c0 = (gt - n*40) * 8;
  const bool lo = (c0 + 4) <= EMB;
  const bool hi = (c0 + 8) <= EMB;
  const float* r1 = xe1 + (size_t)x[2*n]*EMB + c0;
  const float* r2 = xe2 + (size_t)x[2*n+1]*EMB + c0;
  f32x4 a1 = lo ? *(const f32x4*)r1     : (f32x4){0,0,0,0};
  f32x4 a2 = hi ? *(const f32x4*)(r1+4) : (f32x4){0,0,0,0};
  f32x4 b1 = lo ? *(const f32x4*)r2     : (f32x4){0,0,0,0};
  f32x4 b2 = hi ? *(const f32x4*)(r2+4) : (f32x4){0,0,0,0};
  hfrag o;
#pragma unroll
  for (int j = 0; j < 4; j++){
    o[j]   = (f16)(a1[j] + b1[j]);
    o[4+j] = (f16)(a2[j] + b2[j]);
  }
  *(hfrag*)&hb[(size_t)n*EMBP + c0] = o;
}

// ---------------- aggregation: full-lane (thread = node*40 + l40) ----------------
// Every thread independent (no shuffles/LDS) -> nodes may straddle waves/blocks.
// 100% lane utilization vs 62.5% of the 40-of-64-lane layout; waves carrying two
// nodes keep up to 16 gathers in flight. Per-node summation order unchanged.
__global__ __launch_bounds__(256) void k_aggr(
    const f16* __restrict__ h,                  // [*][EMBP] f16 (pre-transformed)
    const int* __restrict__ rowptr,
    const unsigned int* __restrict__ entries,
    const float* __restrict__ t1,               // [6][EMBP] f32 padded
    const float* __restrict__ t2,               // [3][EMBP] f32 padded
    f16* __restrict__ aggr, int N, int Mp)
{
  int gt = blockIdx.x*blockDim.x + threadIdx.x;
  int n = gt / 40;
  if (n >= Mp) return;
  const int c0 = (gt - n*40) * 8;
  float s[8] = {0.f,0.f,0.f,0.f,0.f,0.f,0.f,0.f};
  if (n < N) {
    const int beg = rowptr[n], end = rowptr[n+1];
    int c6[6] = {0,0,0,0,0,0};
    int c3[3] = {0,0,0};
    for (int b0 = beg; b0 < end; b0 += 8) {
      unsigned pe[8]; bool vl[8];
#pragma unroll
      for (int j = 0; j < 8; j++){
        const int idx = b0 + j;
        vl[j] = idx < end;
        pe[j] = entries[vl[j] ? idx : beg];
      }
      hfrag v[8];
#pragma unroll
      for (int j = 0; j < 8; j++)
        v[j] = *(const hfrag*)&h[(size_t)(pe[j] & 0xFFFFF)*EMBP + c0];
#pragma unroll
      for (int j = 0; j < 8; j++){
        if (vl[j]){
          const int bt = (pe[j] >> 20) & 7, bd = (pe[j] >> 24) & 3;
#pragma unroll
          for (int t = 0; t < 6; t++) c6[t] += (bt == t);
#pragma unroll
          for (int t = 0; t < 3; t++) c3[t] += (bd == t);
#pragma unroll
          for (int k = 0; k < 8; k++) s[k] += (float)v[j][k];
        }
      }
    }
#pragma unroll
    for (int t = 0; t < 6; t++) if (c6[t]) {
      const float f = (float)c6[t];
      f32x4 a = *(const f32x4*)&t1[t*EMBP + c0];
      f32x4 b = *(const f32x4*)&t1[t*EMBP + c0 + 4];
#pragma unroll
      for (int k = 0; k < 4; k++){ s[k] += f*a[k]; s[4+k] += f*b[k]; }
    }
#pragma unroll
    for (int t = 0; t < 3; t++) if (c3[t]) {
      const float f = (float)c3[t];
      f32x4 a = *(const f32x4*)&t2[t*EMBP + c0];
      f32x4 b = *(const f32x4*)&t2[t*EMBP + c0 + 4];
#pragma unroll
      for (int k = 0; k < 4; k++){ s[k] += f*a[k]; s[4+k] += f*b[k]; }
    }
  }
  hfrag o;
#pragma unroll
  for (int j = 0; j < 8; j++) o[j] = (f16)s[j];
  *(hfrag*)&aggr[(size_t)n*EMBP + c0] = o;
}

// ---------------- GEMM: 128x128 tile, BK=32, R15-validated 2-stage dbuf ----------
// NOTE: 3-stage counted-vmcnt (R13/R18) corrupts under hipcc even with
// sched_barrier(0) fences — DEAD END, do not retry at source level.
// MODE 0: C = f16 relu -> hid [*][HIDP], chunk-local rows, no stats.
// MODE 1: C = f16 -> hb [Mp][EMBP] (zero pad cols >= EMB), + fused BN stats.
template<int KP, int NCT, int MODE>
__global__ __launch_bounds__(256) void k_gemm(
    const f16* __restrict__ A,
    const f16* __restrict__ Bt,
    const float* __restrict__ bias,
    void* __restrict__ Cv,
    float* __restrict__ part,
    int nBase, int N)
{
  constexpr int NT = KP / 32;
  __shared__ __align__(16) f16 As[2][128*32];
  __shared__ __align__(16) f16 Bs[2][128*32];
  __shared__ float redS[4][64];
  __shared__ float redQ[4][64];
  const int tid = threadIdx.x;
  const int w = tid >> 6, lane = tid & 63;
  const int wr = w >> 1, wc = w & 1;
  const int cl = lane & 15, kg = lane >> 4;

  // XCD-chunked decode (bijective, m204): col-tile fastest -> A-panel L2 reuse.
  const int nwg = gridDim.x;
  const int q = nwg >> 3, rr = nwg & 7;
  const int d = blockIdx.x;
  const int xc = d & 7, jj = d >> 3;
  const int wk = xc*q + (xc < rr ? xc : rr) + jj;
  const int m0 = (wk / NCT) * 128;
  const int n0 = (wk % NCT) * 128;

  // staging: 2 rounds x 256 threads cover 128 rows x 4 segs (16B each).
  // LDS dest linear; global source pre-swizzled seg_g = seg ^ ((row>>1)&3).
  const f16* ag[2]; const f16* bg[2]; int ldst[2];
#pragma unroll
  for (int i = 0; i < 2; i++){
    const int id = i*256 + tid;
    const int row = id >> 2, seg = id & 3;
    const int col = (seg ^ ((row >> 1) & 3)) * 8;
    ag[i] = A  + (size_t)(m0 + row)*KP + col;
    bg[i] = Bt + (size_t)(n0 + row)*KP + col;
    ldst[i] = id * 8;
  }

  auto STAGE = [&](int bb, int kt){
    const int k0 = kt*32;
#pragma unroll
    for (int i = 0; i < 2; i++) gload16(ag[i] + k0, &As[bb][ldst[i]]);
#pragma unroll
    for (int i = 0; i < 2; i++) gload16(bg[i] + k0, &Bs[bb][ldst[i]]);
  };

  f32x4 acc[4][4];
#pragma unroll
  for (int i = 0; i < 4; i++)
#pragma unroll
    for (int j = 0; j < 4; j++)
      acc[i][j] = (f32x4){0.f, 0.f, 0.f, 0.f};

  const int sw3 = (cl >> 1) & 3;   // (row>>1)&3 with row = base16 + cl

  STAGE(0, 0);
#pragma unroll 4
  for (int t = 0; t < NT; ++t){
    const int cur = t & 1;
    if (t + 1 < NT){
      STAGE(cur ^ 1, t + 1);                       // prefetch stays in flight
      asm volatile("s_waitcnt vmcnt(4)" ::: "memory");   // only tile t drained
    } else {
      asm volatile("s_waitcnt vmcnt(0)" ::: "memory");
    }
    __builtin_amdgcn_s_barrier();                  // raw: no full drain
    hfrag af[4], bf[4];
#pragma unroll
    for (int mf = 0; mf < 4; mf++)
      af[mf] = *(const hfrag*)&As[cur][(wr*64 + mf*16 + cl)*32 + ((kg ^ sw3) * 8)];
#pragma unroll
    for (int nf = 0; nf < 4; nf++)
      bf[nf] = *(const hfrag*)&Bs[cur][(wc*64 + nf*16 + cl)*32 + ((kg ^ sw3) * 8)];
#pragma unroll
    for (int mf = 0; mf < 4; mf++)
#pragma unroll
      for (int nf = 0; nf < 4; nf++)
        acc[mf][nf] = __builtin_amdgcn_mfma_f32_16x16x32_f16(af[mf], bf[nf], acc[mf][nf], 0, 0, 0);
    __builtin_amdgcn_s_barrier();                  // buf reads done before re-stage
  }

  const int rg = lane >> 4;
  float ps[4] = {0.f,0.f,0.f,0.f}, pq[4] = {0.f,0.f,0.f,0.f};
#pragma unroll
  for (int mf = 0; mf < 4; mf++) {
#pragma unroll
    for (int nf = 0; nf < 4; nf++) {
      const int col  = n0 + wc*64 + nf*16 + cl;
      const int row0 = m0 + wr*64 + mf*16 + rg*4;
      f32x4 v = acc[mf][nf];
      if (MODE == 0) {
        const float bv = bias[col];
#pragma unroll
        for (int r = 0; r < 4; r++)
          ((f16*)Cv)[(size_t)(row0 + r)*HIDP + col] = (f16)fmaxf(v[r] + bv, 0.f);
      } else {
        const float bv = bias[col];
#pragma unroll
        for (int r = 0; r < 4; r++) {
          const int grow = nBase + row0 + r;
          const float o = v[r] + bv;
          if (col < EMBP)
            ((f16*)Cv)[(size_t)grow*EMBP + col] = (col < EMB) ? (f16)o : (f16)0.f;
          if (grow < N) { ps[nf] += o; pq[nf] += o*o; }
        }
      }
    }
  }

  if (MODE != 0) {
    // deterministic reduce: shfl tree over rg, LDS over wr, per-(panel,colblock)
#pragma unroll
    for (int nf = 0; nf < 4; nf++){
      float s1 = ps[nf], q1 = pq[nf];
      s1 += __shfl_xor(s1, 16); q1 += __shfl_xor(q1, 16);
      s1 += __shfl_xor(s1, 32); q1 += __shfl_xor(q1, 32);
      if (rg == 0){ redS[w][nf*16 + cl] = s1; redQ[w][nf*16 + cl] = q1; }
    }
    __syncthreads();
    if (w < 2 && lane < 16){
      const int gb = (nBase + m0) >> 7;
      float* pS = part + (size_t)gb * (2*EMBP);
#pragma unroll
      for (int nf = 0; nf < 4; nf++){
        const int lc  = nf*16 + lane;
        const int col = n0 + w*64 + nf*16 + lane;
        if (col < EMBP){
          pS[col]        = redS[w][lc] + redS[w+2][lc];
          pS[EMBP + col] = redQ[w][lc] + redQ[w+2][lc];
        }
      }
    }
  }
}

// ---------------- BN finalize (parallel: one block per column) ----------------

__global__ __launch_bounds__(256) void k_bnfin(
    const float* __restrict__ part,
    const float* __restrict__ gamma,
    const float* __restrict__ beta,
    float* __restrict__ scl, float* __restrict__ sft, int N, int RB)
{
  __shared__ float rs[256], rq[256];
  const int c = blockIdx.x;          // 0..EMBP-1
  const int t = threadIdx.x;
  float s = 0.f, q = 0.f;
  for (int gb = t; gb < RB; gb += 256){
    s += part[(size_t)gb*(2*EMBP) + c];
    q += part[(size_t)gb*(2*EMBP) + EMBP + c];
  }
  rs[t] = s; rq[t] = q; __syncthreads();
  for (int off = 128; off > 0; off >>= 1){
    if (t < off){ rs[t] += rs[t+off]; rq[t] += rq[t+off]; }
    __syncthreads();
  }
  if (t == 0){
    if (c < EMB){
      float mean = rs[0] / (float)N;
      float var  = fmaxf(rq[0] / (float)N - mean*mean, 0.f);
      float sc = gamma[c] * rsqrtf(var + BNEPS);
      scl[c] = sc;
      sft[c] = beta[c] - mean*sc;
    } else { scl[c] = 0.f; sft[c] = 0.f; }
  }
}

// mid layers: hb[n][c0..7] = f16(relu(hb*scl+sft)) IN PLACE (elementwise safe)
__global__ void k_bnapply(f16* __restrict__ hb,
                          const float* __restrict__ scl, const float* __restrict__ sft,
                          int N)
{
  int i = blockIdx.x*blockDim.x + threadIdx.x;
  if (i >= N * (EMBP/8)) return;
  const int n = i / (EMBP/8);
  const int c0 = (i - n*(EMBP/8)) * 8;
  hfrag v = *(const hfrag*)&hb[(size_t)n*EMBP + c0];
  hfrag o;
#pragma unroll
  for (int j = 0; j < 8; j++){
    const int c = c0 + j;
    float xv = (c < EMB) ? fmaxf(fmaf((float)v[j], scl[c], sft[c]), 0.f) : 0.f;
    o[j] = (f16)xv;
  }
  *(hfrag*)&hb[(size_t)n*EMBP + c0] = o;
}

// last layer: dout[n][c] = f32(hb[n][c])*scl + sft (no relu)
__global__ void k_bnlast(const f16* __restrict__ hb,
                         const float* __restrict__ scl, const float* __restrict__ sft,
                         float* __restrict__ out, int N){
  int i = blockIdx.x*blockDim.x + threadIdx.x;
  if (i >= N*EMB) return;
  int n = i / EMB, c = i - n*EMB;
  out[i] = (float)hb[(size_t)n*EMBP + c]*scl[c] + sft[c];
}

// ---------------- host ----------------

extern "C" void kernel_launch(void* const* d_in, const int* in_sizes, int n_in,
                              void* d_out, int out_size, void* d_ws, size_t ws_size,
                              hipStream_t stream)
{
  (void)n_in; (void)out_size;
  const int* x  = (const int*)d_in[0];
  const int* ei = (const int*)d_in[1];
  const int* ea = (const int*)d_in[2];
  const float* xe1 = (const float*)d_in[3];
  const float* xe2 = (const float*)d_in[4];
  const float* ee1 = (const float*)d_in[5];
  const float* ee2 = (const float*)d_in[6];
  const float* W1  = (const float*)d_in[7];
  const float* b1  = (const float*)d_in[8];
  const float* W2  = (const float*)d_in[9];
  const float* b2  = (const float*)d_in[10];
  const float* gam = (const float*)d_in[11];
  const float* bet = (const float*)d_in[12];

  const int N  = in_sizes[0] / 2;
  const int E  = in_sizes[1] / 2;
  const int EN = E + N;
  const int Mp = ((N + 127) / 128) * 128;
  const int RB = Mp / 128;
  const int NBLK = (N + 1023) / 1024;

  float* dout = (float*)d_out;

  char* ws = (char*)d_ws;
  size_t off = 0;
  auto alloc = [&](size_t bytes){ size_t o = off; off = (off + bytes + 255) & ~(size_t)255; return o; };

  f16* hb                = (f16*)(ws + alloc((size_t)Mp*EMBP*2));   // h & out (in-place BN)
  f16* aggrb             = (f16*)(ws + alloc((size_t)Mp*EMBP*2));
  unsigned int*  entries = (unsigned int*)(ws + alloc((size_t)EN*4));
  int* rowptr            = (int*)(ws + alloc((size_t)(N+1)*4));
  int* cursor            = (int*)(ws + alloc((size_t)N*4));
  int* deg               = (int*)(ws + alloc((size_t)N*4));
  int* bsum              = (int*)(ws + alloc((size_t)NBLK*4));
  int* boff              = (int*)(ws + alloc((size_t)NBLK*4));
  f16* W1T               = (f16*)(ws + alloc((size_t)NLAYER*HIDP*EMBP*2));
  f16* W2T               = (f16*)(ws + alloc((size_t)NLAYER*EMBP2*HIDP*2));
  float* e1pf            = (float*)(ws + alloc((size_t)NLAYER*6*EMBP*4));
  float* e2pf            = (float*)(ws + alloc((size_t)NLAYER*3*EMBP*4));
  float* b1p             = (float*)(ws + alloc((size_t)NLAYER*HIDP*4));
  float* b2p             = (float*)(ws + alloc((size_t)NLAYER*EMBP*4));
  float* part            = (float*)(ws + alloc((size_t)RB*2*EMBP*4));
  float* scl             = (float*)(ws + alloc((size_t)EMBP*4));
  float* sft             = (float*)(ws + alloc((size_t)EMBP*4));

  if (off >= ws_size) return;
  size_t avail = ws_size - off;
  size_t maxrows = avail / ((size_t)HIDP*2);
  if (maxrows < 128) return;
  int CH = (maxrows >= (size_t)Mp) ? Mp : (int)(maxrows & ~(size_t)127);
  f16* hidc = (f16*)(ws + off);

  // CSR build
  k_zero<<<(N+255)/256, 256, 0, stream>>>((unsigned int*)deg, N);
  k_hist<<<(EN+255)/256, 256, 0, stream>>>(ei, E, N, deg);
  k_scanA<<<NBLK, 256, 0, stream>>>(deg, bsum, N);
  k_scanB<<<1, 64, 0, stream>>>(bsum, boff, rowptr + N, NBLK);
  k_scanC<<<NBLK, 256, 0, stream>>>(deg, boff, rowptr, cursor, N);
  k_fill<<<(EN+255)/256, 256, 0, stream>>>(ei, ea, E, N, cursor, entries);

  // consolidated weight/table prep (1 launch)
  {
    int tot = NLAYER*HIDP*EMBP + NLAYER*EMBP2*HIDP + NLAYER*6*EMBP
            + NLAYER*3*EMBP + NLAYER*HIDP + NLAYER*EMBP;
    k_prep<<<(tot+255)/256, 256, 0, stream>>>(W1, W2, ee1, ee2, b1, b2,
                                              W1T, W2T, e1pf, e2pf, b1p, b2p);
  }

  // h0 f16 into hb (full-lane indexing)
  k_h0<<<((N*40)+255)/256, 256, 0, stream>>>(x, xe1, xe2, hb, N);

  for (int l = 0; l < NLAYER; ++l) {
    k_aggr<<<(((size_t)Mp*40)+255)/256, 256, 0, stream>>>(hb, rowptr, entries,
        e1pf + (size_t)l*6*EMBP, e2pf + (size_t)l*3*EMBP, aggrb, N, Mp);

    for (int base = 0; base < Mp; base += CH) {
      const int rows = (Mp - base < CH) ? (Mp - base) : CH;
      const int nwg1 = (rows/128) * (HIDP/128);
      k_gemm<EMBP, HIDP/128, 0><<<nwg1, 256, 0, stream>>>(
          aggrb + (size_t)base*EMBP, W1T + (size_t)l*HIDP*EMBP,
          b1p + (size_t)l*HIDP, hidc, nullptr, base, N);
      const int nwg2 = (rows/128) * (EMBP2/128);
      k_gemm<HIDP, EMBP2/128, 1><<<nwg2, 256, 0, stream>>>(
          hidc, W2T + (size_t)l*EMBP2*HIDP,
          b2p + (size_t)l*EMBP, hb, part, base, N);
    }
    k_bnfin<<<EMBP, 256, 0, stream>>>(part, gam + (size_t)l*EMB, bet + (size_t)l*EMB, scl, sft, N, RB);
    if (l < NLAYER - 1) {
      int tot = N * (EMBP/8);
      k_bnapply<<<(tot+255)/256, 256, 0, stream>>>(hb, scl, sft, N);
    }
  }
  k_bnlast<<<((N*EMB)+255)/256, 256, 0, stream>>>(hb, scl, sft, dout, N);
}